// Round 1
// baseline (124.470 us; speedup 1.0000x reference)
//
#include <hip/hip_runtime.h>
#include <math.h>

#define NBINS 128
#define NFREQ 64
#define NKER  3
#define GKEYS 8
#define LOG2E 1.4426950408889634f

#if __has_builtin(__builtin_amdgcn_exp2f)
#define EXP2(x) __builtin_amdgcn_exp2f(x)
#else
#define EXP2(x) exp2f(x)
#endif

// ---------------------------------------------------------------------------
// Prep kernel: fold constants.
//  arrC[(f*3+m)*128 + b] = { kappa*cos(mu+ref)*log2e, kappa*sin(mu+ref)*log2e }
//  arrW[(f*3+m)*128 + b] =   weight*exp(-kappa)
//  W1t[b*64 + j]         =   W1[j*128 + b]   (transposed for coalesced epilogue)
// ---------------------------------------------------------------------------
__global__ __launch_bounds__(256) void prep_kernel(
    const float* __restrict__ mu, const float* __restrict__ kappa,
    const float* __restrict__ weight, const float* __restrict__ ref_angles,
    const float* __restrict__ W1,
    float2* __restrict__ arrC, float* __restrict__ arrW, float* __restrict__ W1t)
{
    int idx = blockIdx.x * 256 + threadIdx.x;
    const int NC = NFREQ * NKER * NBINS;  // 24576
    if (idx < NC) {
        int b  = idx & (NBINS - 1);
        int fm = idx >> 7;            // f*3 + m, in [0,192)
        int f  = fm / 3;
        int m  = fm - 3 * f;
        int in = b * (NFREQ * NKER) + f * NKER + m;
        float me = mu[in] + ref_angles[f];
        float s, c;
        sincosf(me, &s, &c);
        float k = kappa[in];
        arrC[idx] = make_float2(k * c * LOG2E, k * s * LOG2E);
        arrW[idx] = weight[in] * expf(-k);
    } else if (idx < NC + NBINS * 64) {
        int q = idx - NC;             // q = b*64 + j
        int j = q & 63;
        int b = q >> 6;
        W1t[q] = W1[j * NBINS + b];
    }
}

// ---------------------------------------------------------------------------
// Main kernel: 128 threads (thread = bin), GKEYS keys per block.
// ---------------------------------------------------------------------------
__global__ __launch_bounds__(128) void main_kernel(
    const float* __restrict__ K, const int* __restrict__ kpos,
    const float* __restrict__ bias,
    const float* __restrict__ b1, const float* __restrict__ W2,
    const float* __restrict__ b2, const float* __restrict__ anchor_raw,
    const float2* __restrict__ arrC, const float* __restrict__ arrW,
    const float* __restrict__ W1t,
    float* __restrict__ out)
{
    __shared__ __align__(16) float magL[NFREQ][GKEYS];
    __shared__ __align__(16) float caL[NFREQ][GKEYS];
    __shared__ __align__(16) float saL[NFREQ][GKEYS];
    __shared__ __align__(16) float Lt[NBINS][GKEYS];   // logits transposed

    const int t  = threadIdx.x;
    const int n0 = blockIdx.x * GKEYS;

    // Stage A: per-(key,freq) magnitude / cos / sin from K components.
    for (int p = t; p < GKEYS * NFREQ; p += 128) {
        int i = p >> 6;        // key in block
        int f = p & 63;        // frequency
        float2 xy = ((const float2*)K)[(n0 + i) * NFREQ + f];
        float r2 = xy.x * xy.x + xy.y * xy.y;
        float mag, ca, sa;
        if (r2 > 0.f) {
            float inv = rsqrtf(r2);
            mag = r2 * inv; ca = xy.x * inv; sa = xy.y * inv;
        } else {
            mag = 0.f; ca = 1.f; sa = 0.f;   // atan2(0,0)=0 -> cos=1,sin=0
        }
        magL[f][i] = mag; caL[f][i] = ca; saL[f][i] = sa;
    }
    float bb = bias[t];
    __syncthreads();

    // Hot loop: logits[n, b=t] accumulation.
    float acc[GKEYS];
    #pragma unroll
    for (int i = 0; i < GKEYS; ++i) acc[i] = 0.f;

    #pragma unroll 2
    for (int f = 0; f < NFREQ; ++f) {
        const float2* pc = arrC + f * (NKER * NBINS) + t;
        const float*  pw = arrW + f * (NKER * NBINS) + t;
        float2 C0 = pc[0], C1 = pc[NBINS], C2 = pc[2 * NBINS];
        float  w0 = pw[0], w1 = pw[NBINS], w2 = pw[2 * NBINS];

        float4 mA = *(const float4*)&magL[f][0];
        float4 mB = *(const float4*)&magL[f][4];
        float4 cA = *(const float4*)&caL[f][0];
        float4 cB = *(const float4*)&caL[f][4];
        float4 sA = *(const float4*)&saL[f][0];
        float4 sB = *(const float4*)&saL[f][4];
        float mg[GKEYS] = {mA.x, mA.y, mA.z, mA.w, mB.x, mB.y, mB.z, mB.w};
        float cc[GKEYS] = {cA.x, cA.y, cA.z, cA.w, cB.x, cB.y, cB.z, cB.w};
        float ss[GKEYS] = {sA.x, sA.y, sA.z, sA.w, sB.x, sB.y, sB.z, sB.w};

        #pragma unroll
        for (int i = 0; i < GKEYS; ++i) {
            float ca = cc[i], sa = ss[i];
            float e0 = EXP2(fmaf(C0.y, sa, C0.x * ca));
            float e1 = EXP2(fmaf(C1.y, sa, C1.x * ca));
            float e2 = EXP2(fmaf(C2.y, sa, C2.x * ca));
            float inner = fmaf(w0, e0, fmaf(w1, e1, w2 * e2));
            acc[i] = fmaf(mg[i], inner, acc[i]);
        }
    }

    // Logits (+bias) into LDS, transposed so the MLP can read float4 per bin.
    {
        float4 v0 = make_float4(acc[0] + bb, acc[1] + bb, acc[2] + bb, acc[3] + bb);
        float4 v1 = make_float4(acc[4] + bb, acc[5] + bb, acc[6] + bb, acc[7] + bb);
        *(float4*)&Lt[t][0] = v0;
        *(float4*)&Lt[t][4] = v1;
    }
    __syncthreads();

    // Epilogue: MLP + position weight + sigmoid.
    // wave 0 (threads 0..63) handles keys 0..3; wave 1 handles keys 4..7.
    const int j  = t & 63;       // hidden unit
    const int wv = t >> 6;       // wave -> key half
    float a0 = b1[j], a1 = a0, a2 = a0, a3 = a0;
    for (int b = 0; b < NBINS; ++b) {
        float w = W1t[b * 64 + j];                    // coalesced, L1-hot
        float4 lv = *(const float4*)&Lt[b][wv * 4];   // LDS broadcast
        a0 = fmaf(lv.x, w, a0);
        a1 = fmaf(lv.y, w, a1);
        a2 = fmaf(lv.z, w, a2);
        a3 = fmaf(lv.w, w, a3);
    }
    float w2j = W2[j];
    float aw0 = log1pf(expf(anchor_raw[0]));
    float aw1 = log1pf(expf(anchor_raw[1]));
    float aw2 = log1pf(expf(anchor_raw[2]));
    float b2v = b2[0];
    float hv[4] = { fmaxf(a0, 0.f) * w2j, fmaxf(a1, 0.f) * w2j,
                    fmaxf(a2, 0.f) * w2j, fmaxf(a3, 0.f) * w2j };

    #pragma unroll
    for (int q = 0; q < 4; ++q) {
        float h = hv[q];
        #pragma unroll
        for (int off = 32; off > 0; off >>= 1) h += __shfl_down(h, off);
        if (j == 0) {
            int n = n0 + wv * 4 + q;
            float mlp = h + b2v;
            float pf  = (float)kpos[n];
            float lp  = log10f(fmaxf(pf, 1.f));
            float w;
            if      (lp < 3.f) w = aw0;
            else if (lp < 4.f) w = fmaf(aw1 - aw0, lp - 3.f, aw0);
            else if (lp < 5.f) w = fmaf(aw2 - aw1, lp - 4.f, aw1);
            else               w = aw2;
            float z = mlp * w;
            out[n] = 1.f / (1.f + expf(-z));
        }
    }
}

extern "C" void kernel_launch(void* const* d_in, const int* in_sizes, int n_in,
                              void* d_out, int out_size, void* d_ws, size_t ws_size,
                              hipStream_t stream)
{
    const float* K    = (const float*)d_in[0];
    const int*   kpos = (const int*)d_in[1];
    const float* ref  = (const float*)d_in[2];
    const float* mu   = (const float*)d_in[3];
    const float* kap  = (const float*)d_in[4];
    const float* wgt  = (const float*)d_in[5];
    const float* bias = (const float*)d_in[6];
    const float* W1   = (const float*)d_in[7];
    const float* b1   = (const float*)d_in[8];
    const float* W2   = (const float*)d_in[9];
    const float* b2   = (const float*)d_in[10];
    const float* anc  = (const float*)d_in[11];
    float* out = (float*)d_out;

    int N = in_sizes[0] / (2 * NFREQ);   // 8192

    char* ws = (char*)d_ws;
    float2* arrC = (float2*)ws;                          // 196608 B
    float*  arrW = (float*)(ws + 196608);                // 98304 B
    float*  W1t  = (float*)(ws + 196608 + 98304);        // 32768 B

    const int prep_threads = NFREQ * NKER * NBINS + NBINS * 64;  // 32768
    prep_kernel<<<(prep_threads + 255) / 256, 256, 0, stream>>>(
        mu, kap, wgt, ref, W1, arrC, arrW, W1t);

    main_kernel<<<N / GKEYS, 128, 0, stream>>>(
        K, kpos, bias, b1, W2, b2, anc, arrC, arrW, W1t, out);
}

// Round 2
// 119.528 us; speedup vs baseline: 1.0413x; 1.0413x over previous
//
#include <hip/hip_runtime.h>
#include <math.h>

#define NBINS 128
#define NFREQ 64
#define NKER  3
#define GKEYS 8
#define LOG2E 1.4426950408889634f

#if __has_builtin(__builtin_amdgcn_exp2f)
#define EXP2(x) __builtin_amdgcn_exp2f(x)
#else
#define EXP2(x) exp2f(x)
#endif

// ---------------------------------------------------------------------------
// Prep kernel: fold constants into 3 packed streams (per (f,b), 9 floats):
//   S1[f*128+b] = { k0*cos(mu0+ref)*log2e, k0*sin(mu0+ref)*log2e,
//                   k1*cos(mu1+ref)*log2e, k1*sin(mu1+ref)*log2e }
//   S2[f*128+b] = { k2*cos(mu2+ref)*log2e, k2*sin(mu2+ref)*log2e,
//                   w0*exp(-k0),           w1*exp(-k1) }
//   S3[f*128+b] =   w2*exp(-k2)
//   W1t[b*64+j] =   W1[j*128+b]
// ---------------------------------------------------------------------------
__global__ __launch_bounds__(256) void prep_kernel(
    const float* __restrict__ mu, const float* __restrict__ kappa,
    const float* __restrict__ weight, const float* __restrict__ ref_angles,
    const float* __restrict__ W1,
    float4* __restrict__ S1, float4* __restrict__ S2, float* __restrict__ S3,
    float* __restrict__ W1t)
{
    int idx = blockIdx.x * 256 + threadIdx.x;
    const int NC = NFREQ * NBINS;  // 8192
    if (idx < NC) {
        int b = idx & (NBINS - 1);
        int f = idx >> 7;
        float ra = ref_angles[f];
        int in = b * (NFREQ * NKER) + f * NKER;   // m = 0,1,2 consecutive
        float c[3], s[3], kk[3], we[3];
        #pragma unroll
        for (int m = 0; m < 3; ++m) {
            float k = kappa[in + m];
            float me = mu[in + m] + ra;
            float sv, cv;
            sincosf(me, &sv, &cv);
            c[m] = k * cv * LOG2E;
            s[m] = k * sv * LOG2E;
            kk[m] = k;
            we[m] = weight[in + m] * expf(-k);
        }
        S1[idx] = make_float4(c[0], s[0], c[1], s[1]);
        S2[idx] = make_float4(c[2], s[2], we[0], we[1]);
        S3[idx] = we[2];
    } else if (idx < NC + NBINS * 64) {
        int q = idx - NC;             // q = b*64 + j
        int j = q & 63;
        int b = q >> 6;
        W1t[q] = W1[j * NBINS + b];
    }
}

// ---------------------------------------------------------------------------
// Main kernel: 128 threads (thread = bin), GKEYS keys per block.
// Register double-buffer: all per-f operands (3 global loads + 6 LDS reads)
// are prefetched one f-iteration ahead so waits land after ~256 cyc of
// independent compute.
// ---------------------------------------------------------------------------
__global__ __launch_bounds__(128) void main_kernel(
    const float* __restrict__ K, const int* __restrict__ kpos,
    const float* __restrict__ bias,
    const float* __restrict__ b1, const float* __restrict__ W2,
    const float* __restrict__ b2, const float* __restrict__ anchor_raw,
    const float4* __restrict__ S1, const float4* __restrict__ S2,
    const float* __restrict__ S3, const float* __restrict__ W1t,
    float* __restrict__ out)
{
    // +1 f row so the f=63 prefetch reads in-bounds garbage (never used)
    __shared__ __align__(16) float magL[NFREQ + 1][GKEYS];
    __shared__ __align__(16) float caL[NFREQ + 1][GKEYS];
    __shared__ __align__(16) float saL[NFREQ + 1][GKEYS];
    __shared__ __align__(16) float Lt[NBINS][GKEYS];   // logits transposed

    const int t  = threadIdx.x;
    const int n0 = blockIdx.x * GKEYS;

    // Stage A: per-(key,freq) magnitude / cos / sin.
    for (int p = t; p < GKEYS * NFREQ; p += 128) {
        int i = p >> 6;        // key in block
        int f = p & 63;        // frequency
        float2 xy = ((const float2*)K)[(n0 + i) * NFREQ + f];
        float r2 = xy.x * xy.x + xy.y * xy.y;
        float mag, ca, sa;
        if (r2 > 0.f) {
            float inv = rsqrtf(r2);
            mag = r2 * inv; ca = xy.x * inv; sa = xy.y * inv;
        } else {
            mag = 0.f; ca = 1.f; sa = 0.f;
        }
        magL[f][i] = mag; caL[f][i] = ca; saL[f][i] = sa;
    }
    float bb = bias[t];
    __syncthreads();

    float acc[GKEYS];
    #pragma unroll
    for (int i = 0; i < GKEYS; ++i) acc[i] = 0.f;

    const float4* S1p = S1 + t;
    const float4* S2p = S2 + t;
    const float*  S3p = S3 + t;

    // Preload f=0 operands.
    float4 c1 = S1p[0];
    float4 c2 = S2p[0];
    float  w2v = S3p[0];
    float4 mA = *(const float4*)&magL[0][0];
    float4 mB = *(const float4*)&magL[0][4];
    float4 cA = *(const float4*)&caL[0][0];
    float4 cB = *(const float4*)&caL[0][4];
    float4 sA = *(const float4*)&saL[0][0];
    float4 sB = *(const float4*)&saL[0][4];

    #pragma unroll 4
    for (int f = 0; f < NFREQ; ++f) {
        // ---- prefetch f+1 (reads padding row / wrap row at f=63; unused) ----
        int fn = f + 1;
        float4 nc1 = S1p[(fn < NFREQ ? fn : 0) * NBINS];
        float4 nc2 = S2p[(fn < NFREQ ? fn : 0) * NBINS];
        float  nw2 = S3p[(fn < NFREQ ? fn : 0) * NBINS];
        float4 nmA = *(const float4*)&magL[fn][0];
        float4 nmB = *(const float4*)&magL[fn][4];
        float4 ncA = *(const float4*)&caL[fn][0];
        float4 ncB = *(const float4*)&caL[fn][4];
        float4 nsA = *(const float4*)&saL[fn][0];
        float4 nsB = *(const float4*)&saL[fn][4];

        // ---- compute f from current registers ----
        #define KEYSTEP(CA, SA, MG, ACCI) {                                   \
            float e0 = EXP2(fmaf(c1.y, SA, c1.x * CA));                       \
            float e1 = EXP2(fmaf(c1.w, SA, c1.z * CA));                       \
            float e2 = EXP2(fmaf(c2.y, SA, c2.x * CA));                       \
            acc[ACCI] = fmaf(MG, fmaf(c2.z, e0, fmaf(c2.w, e1, w2v * e2)),    \
                             acc[ACCI]); }
        KEYSTEP(cA.x, sA.x, mA.x, 0)
        KEYSTEP(cA.y, sA.y, mA.y, 1)
        KEYSTEP(cA.z, sA.z, mA.z, 2)
        KEYSTEP(cA.w, sA.w, mA.w, 3)
        KEYSTEP(cB.x, sB.x, mB.x, 4)
        KEYSTEP(cB.y, sB.y, mB.y, 5)
        KEYSTEP(cB.z, sB.z, mB.z, 6)
        KEYSTEP(cB.w, sB.w, mB.w, 7)
        #undef KEYSTEP

        // ---- rotate ----
        c1 = nc1; c2 = nc2; w2v = nw2;
        mA = nmA; mB = nmB; cA = ncA; cB = ncB; sA = nsA; sB = nsB;
    }

    // Logits (+bias) into LDS, transposed for the MLP.
    {
        float4 v0 = make_float4(acc[0] + bb, acc[1] + bb, acc[2] + bb, acc[3] + bb);
        float4 v1 = make_float4(acc[4] + bb, acc[5] + bb, acc[6] + bb, acc[7] + bb);
        *(float4*)&Lt[t][0] = v0;
        *(float4*)&Lt[t][4] = v1;
    }
    __syncthreads();

    // Epilogue: MLP + position weight + sigmoid.
    const int j  = t & 63;       // hidden unit
    const int wv = t >> 6;       // wave -> key half
    float a0 = b1[j], a1 = a0, a2 = a0, a3 = a0;
    for (int b = 0; b < NBINS; ++b) {
        float w = W1t[b * 64 + j];                    // coalesced, L1-hot
        float4 lv = *(const float4*)&Lt[b][wv * 4];   // LDS broadcast
        a0 = fmaf(lv.x, w, a0);
        a1 = fmaf(lv.y, w, a1);
        a2 = fmaf(lv.z, w, a2);
        a3 = fmaf(lv.w, w, a3);
    }
    float w2j = W2[j];
    float aw0 = log1pf(expf(anchor_raw[0]));
    float aw1 = log1pf(expf(anchor_raw[1]));
    float aw2 = log1pf(expf(anchor_raw[2]));
    float b2v = b2[0];
    float hv[4] = { fmaxf(a0, 0.f) * w2j, fmaxf(a1, 0.f) * w2j,
                    fmaxf(a2, 0.f) * w2j, fmaxf(a3, 0.f) * w2j };

    #pragma unroll
    for (int q = 0; q < 4; ++q) {
        float h = hv[q];
        #pragma unroll
        for (int off = 32; off > 0; off >>= 1) h += __shfl_down(h, off);
        if (j == 0) {
            int n = n0 + wv * 4 + q;
            float mlp = h + b2v;
            float pf  = (float)kpos[n];
            float lp  = log10f(fmaxf(pf, 1.f));
            float w;
            if      (lp < 3.f) w = aw0;
            else if (lp < 4.f) w = fmaf(aw1 - aw0, lp - 3.f, aw0);
            else if (lp < 5.f) w = fmaf(aw2 - aw1, lp - 4.f, aw1);
            else               w = aw2;
            float z = mlp * w;
            out[n] = 1.f / (1.f + expf(-z));
        }
    }
}

extern "C" void kernel_launch(void* const* d_in, const int* in_sizes, int n_in,
                              void* d_out, int out_size, void* d_ws, size_t ws_size,
                              hipStream_t stream)
{
    const float* K    = (const float*)d_in[0];
    const int*   kpos = (const int*)d_in[1];
    const float* ref  = (const float*)d_in[2];
    const float* mu   = (const float*)d_in[3];
    const float* kap  = (const float*)d_in[4];
    const float* wgt  = (const float*)d_in[5];
    const float* bias = (const float*)d_in[6];
    const float* W1   = (const float*)d_in[7];
    const float* b1   = (const float*)d_in[8];
    const float* W2   = (const float*)d_in[9];
    const float* b2   = (const float*)d_in[10];
    const float* anc  = (const float*)d_in[11];
    float* out = (float*)d_out;

    int N = in_sizes[0] / (2 * NFREQ);   // 8192

    // Workspace layout (all 16B aligned):
    //   S1: 8192 float4 = 131072 B
    //   S2: 8192 float4 = 131072 B
    //   S3: 8192 float  =  32768 B
    //   W1t: 8192 float =  32768 B
    char* ws = (char*)d_ws;
    float4* S1  = (float4*)ws;
    float4* S2  = (float4*)(ws + 131072);
    float*  S3  = (float*)(ws + 262144);
    float*  W1t = (float*)(ws + 294912);

    const int prep_threads = NFREQ * NBINS + NBINS * 64;  // 16384
    prep_kernel<<<(prep_threads + 255) / 256, 256, 0, stream>>>(
        mu, kap, wgt, ref, W1, S1, S2, S3, W1t);

    main_kernel<<<N / GKEYS, 128, 0, stream>>>(
        K, kpos, bias, b1, W2, b2, anc, S1, S2, S3, W1t, out);
}

// Round 3
// 91.110 us; speedup vs baseline: 1.3662x; 1.3119x over previous
//
#include <hip/hip_runtime.h>
#include <math.h>

#define NBINS 128
#define NFREQ 64
#define NH    4                  // harmonics kept (I5(1)=2.7e-4 dropped -> ~1e-4 logit err)
#define NSEG  (2*NH+1)           // 9 feature segments: mag, (cos k, sin k) k=1..4
#define KDIM  (NSEG*NFREQ)       // 576
#define KSTEPS (KDIM/32)         // 18
#define ROWF  (KDIM+8)           // 584 f16 = 1168 B row (16B-mult, bank-stride 4 -> 2-way free)
#define ROWL  (NBINS+8)          // 136 f16 = 272 B row
#define ROWP  68

typedef _Float16 f16x8 __attribute__((ext_vector_type(8)));
typedef _Float16 f16x2 __attribute__((ext_vector_type(2)));
typedef float    f32x4 __attribute__((ext_vector_type(4)));

#define MFMA16(A,B,C) __builtin_amdgcn_mfma_f32_16x16x32_f16((A),(B),(C),0,0,0)

// ---------------------------------------------------------------------------
// Prep: Fourier-fold the von-Mises kernel into GEMM coefficients.
//   C[bin][q], q = seg*64 + f:  seg0 = sum_m w e^-k I0;
//   seg(2k-1) = sum_m w e^-k 2 Ik cos(k*mu_eff); seg(2k) = ... sin(k*mu_eff)
// Stored in MFMA B-fragment order: Cfrag[(ks*8+bt)*512 + lane*8 + elem],
//   bin = bt*16 + (lane&15), q = ks*32 + (lane>>4)*8 + elem.
// Also W1 -> fp16 (row-major [j][bin], B-fragment-readable directly).
// ---------------------------------------------------------------------------
__global__ __launch_bounds__(256) void prep_kernel(
    const float* __restrict__ mu, const float* __restrict__ kappa,
    const float* __restrict__ weight, const float* __restrict__ ref,
    const float* __restrict__ W1,
    _Float16* __restrict__ Cfrag, _Float16* __restrict__ W1h)
{
    int u = blockIdx.x * 256 + threadIdx.x;   // 0..8191
    W1h[u] = (_Float16)W1[u];                 // 64*128 = 8192 elems

    int f = u >> 7;
    int bin = u & 127;
    float ra = ref[f];
    float A[NH + 1], B[NH + 1];
    #pragma unroll
    for (int k = 0; k <= NH; ++k) { A[k] = 0.f; B[k] = 0.f; }

    for (int m = 0; m < 3; ++m) {
        int idx = (bin * NFREQ + f) * 3 + m;   // (B,F,M) layout
        float kap = kappa[idx];
        float wgt = weight[idx];
        float mue = mu[idx] + ra;
        // modified Bessel I_0..I_NH(kap) via power series (converges fast, kap~1)
        float I[NH + 1];
        float x2 = kap * 0.5f, x2sq = x2 * x2;
        float fact = 1.f, xk = 1.f;
        #pragma unroll
        for (int k = 0; k <= NH; ++k) {
            if (k > 0) { fact *= (float)k; xk *= x2; }
            float term = xk / fact;
            float s = term;
            for (int j = 1; j <= 12; ++j) {
                term *= x2sq / ((float)j * (float)(j + k));
                s += term;
            }
            I[k] = s;
        }
        float e = expf(-kap) * wgt;
        float c1, s1; sincosf(mue, &s1, &c1);
        float ck = 1.f, sk = 0.f;
        A[0] += e * I[0];
        #pragma unroll
        for (int k = 1; k <= NH; ++k) {
            float cn = ck * c1 - sk * s1;
            float sn = sk * c1 + ck * s1;
            ck = cn; sk = sn;                 // cos(k*mue), sin(k*mue)
            A[k] += e * 2.f * I[k] * ck;
            B[k] += e * 2.f * I[k] * sk;
        }
    }
    int bt = bin >> 4;
    #pragma unroll
    for (int seg = 0; seg < NSEG; ++seg) {
        float v = (seg == 0) ? A[0] : ((seg & 1) ? A[(seg + 1) >> 1] : B[seg >> 1]);
        int q = seg * NFREQ + f;
        int ks = q >> 5, kk = q & 31;
        int lane = (bin & 15) | (((kk >> 3) & 3) << 4);
        int elem = kk & 7;
        size_t flat = ((size_t)(ks * 8 + bt) * 64 + lane) * 8 + elem;
        Cfrag[flat] = (_Float16)v;
    }
}

// ---------------------------------------------------------------------------
// Main: 256 threads (4 waves), 32 keys/block, 256 blocks.
// Phase 1: build Phi features in LDS (no trig: mag*cos(kθ) via rotation of (x,y)).
// Phase 2: logits = Phi(32x576) x C^T(576x128) via fp16 MFMA, wave w = bins 32w..+31.
// Phase 3: MLP h = relu(logits*W1^T + b1) via MFMA; out = sigmoid((h*W2+b2)*posw).
// ---------------------------------------------------------------------------
__global__ __launch_bounds__(256) void main_kernel(
    const float* __restrict__ K, const int* __restrict__ kpos,
    const float* __restrict__ bias, const float* __restrict__ b1,
    const float* __restrict__ W2, const float* __restrict__ b2,
    const float* __restrict__ anchor_raw,
    const _Float16* __restrict__ Cfrag, const _Float16* __restrict__ W1h,
    float* __restrict__ out)
{
    __shared__ _Float16 PhiF[32 * ROWF];   // 37376 B
    __shared__ _Float16 LgF[32 * ROWL];    //  8704 B
    __shared__ float    Ps[32 * ROWP];     //  8704 B
    __shared__ float    Pr[256];           //  1024 B  (total ~55.8 KB)

    const int t  = threadIdx.x;
    const int n0 = blockIdx.x * 32;

    // ---- Phase 1: features ----
    {
        int f2 = t & 31, krow = t >> 5;
        #pragma unroll
        for (int it = 0; it < 4; ++it) {
            int key = krow + 8 * it;
            float4 xy = *(const float4*)(K + (size_t)(n0 + key) * 128 + f2 * 4);
            float vs[2][NSEG];
            #pragma unroll
            for (int e = 0; e < 2; ++e) {
                float x = e ? xy.z : xy.x;
                float y = e ? xy.w : xy.y;
                float r2 = x * x + y * y;
                float inv = r2 > 0.f ? rsqrtf(r2) : 0.f;
                vs[e][0] = r2 * inv;          // mag
                float ca = x * inv, sa = y * inv;
                float mc = x, ms = y;         // mag*cosθ, mag*sinθ
                vs[e][1] = mc; vs[e][2] = ms;
                #pragma unroll
                for (int h = 2; h <= NH; ++h) {
                    float mc2 = mc * ca - ms * sa;
                    float ms2 = ms * ca + mc * sa;
                    mc = mc2; ms = ms2;
                    vs[e][2 * h - 1] = mc; vs[e][2 * h] = ms;
                }
            }
            _Float16* dst = PhiF + key * ROWF + 2 * f2;
            #pragma unroll
            for (int s = 0; s < NSEG; ++s) {
                f16x2 pk; pk.x = (_Float16)vs[0][s]; pk.y = (_Float16)vs[1][s];
                *(f16x2*)(dst + s * 64) = pk;
            }
        }
    }
    __syncthreads();

    // ---- Phase 2: feature GEMM ----
    const int l = t & 63, w = t >> 6;
    f32x4 acc[2][2] = {};
    const _Float16* phA0 = PhiF + (l & 15) * ROWF + (l >> 4) * 8;
    const _Float16* phA1 = phA0 + 16 * ROWF;
    const _Float16* cb   = Cfrag + (size_t)(2 * w) * 512 + (size_t)l * 8;
    #define LA(PH, KS) (*(const f16x8*)((PH) + (KS) * 32))
    #define LB(KS, BT) (*(const f16x8*)(cb + ((size_t)(KS) * 8 + (BT)) * 512))

    f16x8 b00 = LB(0, 0), b01 = LB(0, 1), b10 = LB(1, 0), b11 = LB(1, 1);
    f16x8 a0 = LA(phA0, 0), a1 = LA(phA1, 0);
    #pragma unroll
    for (int ks = 0; ks < KSTEPS; ++ks) {
        int kb = ks + 2 < KSTEPS ? ks + 2 : ks;   // B prefetch depth 2
        f16x8 nb0 = LB(kb, 0), nb1 = LB(kb, 1);
        int ka = ks + 1 < KSTEPS ? ks + 1 : ks;   // A prefetch depth 1 (LDS)
        f16x8 na0 = LA(phA0, ka), na1 = LA(phA1, ka);
        acc[0][0] = MFMA16(a0, b00, acc[0][0]);
        acc[0][1] = MFMA16(a0, b01, acc[0][1]);
        acc[1][0] = MFMA16(a1, b00, acc[1][0]);
        acc[1][1] = MFMA16(a1, b01, acc[1][1]);
        a0 = na0; a1 = na1;
        b00 = b10; b01 = b11; b10 = nb0; b11 = nb1;
    }
    #undef LA
    #undef LB

    // logits (+bias) -> LDS as fp16 in A-fragment-readable layout [key][bin]
    #pragma unroll
    for (int kt = 0; kt < 2; ++kt) {
        #pragma unroll
        for (int bt = 0; bt < 2; ++bt) {
            int bin = 32 * w + bt * 16 + (l & 15);
            float bb = bias[bin];
            #pragma unroll
            for (int r = 0; r < 4; ++r) {
                int key = kt * 16 + (l >> 4) * 4 + r;  // D: col=lane&15, row=(lane>>4)*4+r
                LgF[key * ROWL + bin] = (_Float16)(acc[kt][bt][r] + bb);
            }
        }
    }
    __syncthreads();

    // ---- Phase 3: MLP layer 1 via MFMA (M=32 keys, N=64 j, K=128 bins) ----
    f32x4 hacc[2] = {};
    const _Float16* lgA0 = LgF + (l & 15) * ROWL + (l >> 4) * 8;
    const _Float16* lgA1 = lgA0 + 16 * ROWL;
    const _Float16* wb   = W1h + (size_t)(16 * w + (l & 15)) * 128 + (l >> 4) * 8;
    #pragma unroll
    for (int ks = 0; ks < 4; ++ks) {
        f16x8 bfr = *(const f16x8*)(wb + ks * 32);
        f16x8 a0m = *(const f16x8*)(lgA0 + ks * 32);
        f16x8 a1m = *(const f16x8*)(lgA1 + ks * 32);
        hacc[0] = MFMA16(a0m, bfr, hacc[0]);
        hacc[1] = MFMA16(a1m, bfr, hacc[1]);
    }
    {
        int j = 16 * w + (l & 15);
        float b1j = b1[j], w2j = W2[j];
        #pragma unroll
        for (int kt = 0; kt < 2; ++kt) {
            #pragma unroll
            for (int r = 0; r < 4; ++r) {
                int key = kt * 16 + (l >> 4) * 4 + r;
                float h = hacc[kt][r] + b1j;
                Ps[key * ROWP + j] = fmaxf(h, 0.f) * w2j;
            }
        }
    }
    __syncthreads();

    // reduce 64 j per key
    {
        int key = t >> 3, g = t & 7;
        const float* p = Ps + key * ROWP + g * 8;
        Pr[t] = ((p[0] + p[1]) + (p[2] + p[3])) + ((p[4] + p[5]) + (p[6] + p[7]));
    }
    __syncthreads();
    if (t < 32) {
        const float* p = Pr + t * 8;
        float s = ((p[0] + p[1]) + (p[2] + p[3])) + ((p[4] + p[5]) + (p[6] + p[7]));
        float mlp = s + b2[0];
        float aw0 = log1pf(expf(anchor_raw[0]));
        float aw1 = log1pf(expf(anchor_raw[1]));
        float aw2 = log1pf(expf(anchor_raw[2]));
        int n = n0 + t;
        float pf = (float)kpos[n];
        float lp = log10f(fmaxf(pf, 1.f));
        float wgt;
        if      (lp < 3.f) wgt = aw0;
        else if (lp < 4.f) wgt = fmaf(aw1 - aw0, lp - 3.f, aw0);
        else if (lp < 5.f) wgt = fmaf(aw2 - aw1, lp - 4.f, aw1);
        else               wgt = aw2;
        float z = mlp * wgt;
        out[n] = 1.f / (1.f + expf(-z));
    }
}

extern "C" void kernel_launch(void* const* d_in, const int* in_sizes, int n_in,
                              void* d_out, int out_size, void* d_ws, size_t ws_size,
                              hipStream_t stream)
{
    const float* K    = (const float*)d_in[0];
    const int*   kpos = (const int*)d_in[1];
    const float* ref  = (const float*)d_in[2];
    const float* mu   = (const float*)d_in[3];
    const float* kap  = (const float*)d_in[4];
    const float* wgt  = (const float*)d_in[5];
    const float* bias = (const float*)d_in[6];
    const float* W1   = (const float*)d_in[7];
    const float* b1   = (const float*)d_in[8];
    const float* W2   = (const float*)d_in[9];
    const float* b2   = (const float*)d_in[10];
    const float* anc  = (const float*)d_in[11];
    float* out = (float*)d_out;

    int N = in_sizes[0] / (2 * NFREQ);   // 8192

    // Workspace: Cfrag 18*8*512 f16 = 147456 B; W1h 8192 f16 = 16384 B
    char* ws = (char*)d_ws;
    _Float16* Cfrag = (_Float16*)ws;
    _Float16* W1h   = (_Float16*)(ws + 147456);

    prep_kernel<<<32, 256, 0, stream>>>(mu, kap, wgt, ref, W1, Cfrag, W1h);
    main_kernel<<<N / 32, 256, 0, stream>>>(K, kpos, bias, b1, W2, b2, anc,
                                            Cfrag, W1h, out);
}

// Round 4
// 85.755 us; speedup vs baseline: 1.4515x; 1.0624x over previous
//
#include <hip/hip_runtime.h>
#include <math.h>

#define NBINS 128
#define NFREQ 64
#define NH    4                  // harmonics kept (I5(1)=2.7e-4 dropped)
#define NSEG  (2*NH+1)           // 9 feature segments
#define KDIM  (NSEG*NFREQ)       // 576
#define KSTEPS (KDIM/32)         // 18
#define ROWF  (KDIM+8)           // 584 f16 row
#define ROWL  (NBINS+8)          // 136 f16 row
#define ROWP  68

typedef _Float16 f16x8 __attribute__((ext_vector_type(8)));
typedef _Float16 f16x2 __attribute__((ext_vector_type(2)));
typedef float    f32x4 __attribute__((ext_vector_type(4)));

#define MFMA16(A,B,C) __builtin_amdgcn_mfma_f32_16x16x32_f16((A),(B),(C),0,0,0)

// ---------------------------------------------------------------------------
// Prep: Fourier-fold von-Mises into GEMM coefficients.
// 128 blocks x 192 threads; thread = (m, group), group = (bin,f).
// Bessel series uses compile-time reciprocals (no divisions).
// LDS-reduce over m, then m=0 lane scatters 9 fp16 coefs in B-fragment order.
// ---------------------------------------------------------------------------
__global__ __launch_bounds__(192) void prep_kernel(
    const float* __restrict__ mu, const float* __restrict__ kappa,
    const float* __restrict__ weight, const float* __restrict__ ref,
    const float* __restrict__ W1,
    _Float16* __restrict__ Cfrag, _Float16* __restrict__ W1h)
{
    __shared__ float red[3][64][10];

    const int t = threadIdx.x;           // 0..191
    const int m = t >> 6;                // 0..2
    const int g = t & 63;                // 0..63
    const int G = blockIdx.x * 64 + g;   // (bin,f) group, 0..8191
    const int f = G & 63;

    // W1 -> fp16 (8192 elems over 24576 threads)
    int wid = blockIdx.x * 192 + t;
    if (wid < NBINS * 64) W1h[wid] = (_Float16)W1[wid];

    const int idx = G * 3 + m;           // (bin*64+f)*3 + m  — coalesced-ish
    float kap = kappa[idx];
    float wgt = weight[idx];
    float mue = mu[idx] + ref[f];

    // I_0..I_4(kap) power series; all divisors are compile-time reciprocals.
    float I[NH + 1];
    {
        const float rfact[NH + 1] = {1.f, 1.f, 0.5f, 1.f / 6.f, 1.f / 24.f};
        float x2 = kap * 0.5f, x2sq = x2 * x2;
        float xk = 1.f;
        #pragma unroll
        for (int k = 0; k <= NH; ++k) {
            if (k > 0) xk *= x2;
            float term = xk * rfact[k];
            float s = term;
            #pragma unroll
            for (int j = 1; j <= 12; ++j) {
                term *= x2sq * (1.f / ((float)j * (float)(j + k)));
                s += term;
            }
            I[k] = s;
        }
    }
    float e = expf(-kap) * wgt;
    float c1, s1; sincosf(mue, &s1, &c1);
    float ck = 1.f, sk = 0.f;
    red[m][g][0] = e * I[0];
    #pragma unroll
    for (int k = 1; k <= NH; ++k) {
        float cn = ck * c1 - sk * s1;
        float sn = sk * c1 + ck * s1;
        ck = cn; sk = sn;                // cos(k*mue), sin(k*mue)
        red[m][g][2 * k - 1] = e * 2.f * I[k] * ck;
        red[m][g][2 * k]     = e * 2.f * I[k] * sk;
    }
    __syncthreads();

    if (t < 64) {
        int G2 = blockIdx.x * 64 + t;
        int bin = G2 >> 6, ff = G2 & 63, bt = bin >> 4;
        #pragma unroll
        for (int seg = 0; seg < NSEG; ++seg) {
            float v = red[0][t][seg] + red[1][t][seg] + red[2][t][seg];
            int q = seg * NFREQ + ff;
            int ks = q >> 5, kk = q & 31;
            int lane = (bin & 15) | (((kk >> 3) & 3) << 4);
            int elem = kk & 7;
            Cfrag[((size_t)(ks * 8 + bt) * 64 + lane) * 8 + elem] = (_Float16)v;
        }
    }
}

// ---------------------------------------------------------------------------
// Main: 512 blocks x 256 threads (4 waves), 16 keys/block -> 2 blocks/CU.
// Phase 1: Phi features in LDS (rotation recurrence, no trig).
// Phase 2: logits(16x128) = Phi(16x576) x C^T via fp16 MFMA; wave w = 32 bins.
// Phase 3: MLP via MFMA (wave w = 16 hidden units); reduce; sigmoid epilogue.
// ---------------------------------------------------------------------------
__global__ __launch_bounds__(256) void main_kernel(
    const float* __restrict__ K, const int* __restrict__ kpos,
    const float* __restrict__ bias, const float* __restrict__ b1,
    const float* __restrict__ W2, const float* __restrict__ b2,
    const float* __restrict__ anchor_raw,
    const _Float16* __restrict__ Cfrag, const _Float16* __restrict__ W1h,
    float* __restrict__ out)
{
    __shared__ _Float16 PhiF[16 * ROWF];   // 18688 B
    __shared__ _Float16 LgF[16 * ROWL];    //  4352 B
    __shared__ float    Ps[16 * ROWP];     //  4352 B
    __shared__ float    Pr[256];           //  1024 B   (~28.4 KB total)

    const int t  = threadIdx.x;
    const int n0 = blockIdx.x * 16;

    // ---- Phase 1: features (16 keys x 32 float4-groups = 512 items) ----
    #pragma unroll
    for (int it = 0; it < 2; ++it) {
        int p = it * 256 + t;
        int key = p >> 5, f2 = p & 31;
        float4 xy = *(const float4*)(K + (size_t)(n0 + key) * 128 + f2 * 4);
        float vs[2][NSEG];
        #pragma unroll
        for (int e = 0; e < 2; ++e) {
            float x = e ? xy.z : xy.x;
            float y = e ? xy.w : xy.y;
            float r2 = x * x + y * y;
            float inv = r2 > 0.f ? rsqrtf(r2) : 0.f;
            vs[e][0] = r2 * inv;          // mag
            float ca = x * inv, sa = y * inv;
            float mc = x, ms = y;         // mag*cos(kθ), mag*sin(kθ)
            vs[e][1] = mc; vs[e][2] = ms;
            #pragma unroll
            for (int h = 2; h <= NH; ++h) {
                float mc2 = mc * ca - ms * sa;
                float ms2 = ms * ca + mc * sa;
                mc = mc2; ms = ms2;
                vs[e][2 * h - 1] = mc; vs[e][2 * h] = ms;
            }
        }
        _Float16* dst = PhiF + key * ROWF + 2 * f2;
        #pragma unroll
        for (int s = 0; s < NSEG; ++s) {
            f16x2 pk; pk.x = (_Float16)vs[0][s]; pk.y = (_Float16)vs[1][s];
            *(f16x2*)(dst + s * 64) = pk;
        }
    }
    __syncthreads();

    // ---- Phase 2: feature GEMM (wave w -> bins 32w..32w+31) ----
    const int l = t & 63, w = t >> 6;
    f32x4 acc[2] = {};
    const _Float16* phA = PhiF + (l & 15) * ROWF + (l >> 4) * 8;
    const _Float16* cb  = Cfrag + (size_t)(2 * w) * 512 + (size_t)l * 8;
    #define LA(KS) (*(const f16x8*)(phA + (KS) * 32))
    #define LB(KS, BT) (*(const f16x8*)(cb + ((size_t)(KS) * 8 + (BT)) * 512))

    f16x8 b00 = LB(0, 0), b01 = LB(0, 1), b10 = LB(1, 0), b11 = LB(1, 1);
    f16x8 a0 = LA(0);
    #pragma unroll
    for (int ks = 0; ks < KSTEPS; ++ks) {
        int kb = ks + 2 < KSTEPS ? ks + 2 : KSTEPS - 1;   // B prefetch depth 2
        f16x8 nb0 = LB(kb, 0), nb1 = LB(kb, 1);
        int ka = ks + 1 < KSTEPS ? ks + 1 : KSTEPS - 1;   // A prefetch depth 1
        f16x8 na0 = LA(ka);
        acc[0] = MFMA16(a0, b00, acc[0]);
        acc[1] = MFMA16(a0, b01, acc[1]);
        a0 = na0;
        b00 = b10; b01 = b11; b10 = nb0; b11 = nb1;
    }
    #undef LA
    #undef LB

    // logits (+bias) -> LDS fp16, [key][bin] (A-fragment-readable)
    #pragma unroll
    for (int bt = 0; bt < 2; ++bt) {
        int bin = 32 * w + bt * 16 + (l & 15);
        float bbv = bias[bin];
        #pragma unroll
        for (int r = 0; r < 4; ++r) {
            int key = (l >> 4) * 4 + r;   // D: col=lane&15, row=(lane>>4)*4+r
            LgF[key * ROWL + bin] = (_Float16)(acc[bt][r] + bbv);
        }
    }
    __syncthreads();

    // ---- Phase 3: MLP layer 1 (M=16 keys, N=64 j, K=128 bins); wave w -> 16 j ----
    f32x4 hacc = {};
    const _Float16* lgA = LgF + (l & 15) * ROWL + (l >> 4) * 8;
    const _Float16* wb  = W1h + (size_t)(16 * w + (l & 15)) * 128 + (l >> 4) * 8;
    #pragma unroll
    for (int ks = 0; ks < 4; ++ks) {
        f16x8 bfr = *(const f16x8*)(wb + ks * 32);
        f16x8 am  = *(const f16x8*)(lgA + ks * 32);
        hacc = MFMA16(am, bfr, hacc);
    }
    {
        int j = 16 * w + (l & 15);
        float b1j = b1[j], w2j = W2[j];
        #pragma unroll
        for (int r = 0; r < 4; ++r) {
            int key = (l >> 4) * 4 + r;
            float h = hacc[r] + b1j;
            Ps[key * ROWP + j] = fmaxf(h, 0.f) * w2j;
        }
    }
    __syncthreads();

    // reduce 64 j per key: stage 1 (16 threads/key x 4 elems), stage 2 (16 keys)
    {
        int key = t >> 4, gg = t & 15;
        const float* p = Ps + key * ROWP + gg * 4;
        Pr[t] = (p[0] + p[1]) + (p[2] + p[3]);
    }
    __syncthreads();
    if (t < 16) {
        const float* p = Pr + t * 16;
        float s = (((p[0] + p[1]) + (p[2] + p[3])) + ((p[4] + p[5]) + (p[6] + p[7])))
                + (((p[8] + p[9]) + (p[10] + p[11])) + ((p[12] + p[13]) + (p[14] + p[15])));
        float mlp = s + b2[0];
        float aw0 = log1pf(expf(anchor_raw[0]));
        float aw1 = log1pf(expf(anchor_raw[1]));
        float aw2 = log1pf(expf(anchor_raw[2]));
        int n = n0 + t;
        float pf = (float)kpos[n];
        float lp = log10f(fmaxf(pf, 1.f));
        float wgt;
        if      (lp < 3.f) wgt = aw0;
        else if (lp < 4.f) wgt = fmaf(aw1 - aw0, lp - 3.f, aw0);
        else if (lp < 5.f) wgt = fmaf(aw2 - aw1, lp - 4.f, aw1);
        else               wgt = aw2;
        float z = mlp * wgt;
        out[n] = 1.f / (1.f + expf(-z));
    }
}

extern "C" void kernel_launch(void* const* d_in, const int* in_sizes, int n_in,
                              void* d_out, int out_size, void* d_ws, size_t ws_size,
                              hipStream_t stream)
{
    const float* K    = (const float*)d_in[0];
    const int*   kpos = (const int*)d_in[1];
    const float* ref  = (const float*)d_in[2];
    const float* mu   = (const float*)d_in[3];
    const float* kap  = (const float*)d_in[4];
    const float* wgt  = (const float*)d_in[5];
    const float* bias = (const float*)d_in[6];
    const float* W1   = (const float*)d_in[7];
    const float* b1   = (const float*)d_in[8];
    const float* W2   = (const float*)d_in[9];
    const float* b2   = (const float*)d_in[10];
    const float* anc  = (const float*)d_in[11];
    float* out = (float*)d_out;

    int N = in_sizes[0] / (2 * NFREQ);   // 8192

    // Workspace: Cfrag 18*8*512 f16 = 147456 B; W1h 8192 f16 = 16384 B
    char* ws = (char*)d_ws;
    _Float16* Cfrag = (_Float16*)ws;
    _Float16* W1h   = (_Float16*)(ws + 147456);

    prep_kernel<<<128, 192, 0, stream>>>(mu, kap, wgt, ref, W1, Cfrag, W1h);
    main_kernel<<<N / 16, 256, 0, stream>>>(K, kpos, bias, b1, W2, b2, anc,
                                            Cfrag, W1h, out);
}